// Round 4
// baseline (76.471 us; speedup 1.0000x reference)
//
#include <hip/hip_runtime.h>
#include <math.h>

#define NJ 128
#define HH 512
#define WW 512
#define FEPS 1e-7f

// par layout: AoS, 16 floats per instance j (aligned for s_load / dwordx4):
//  0 mmx, 1 mmy, 2 ia, 3 ib2, 4 ic, 5 pad, 6 ls0, 7 ls1,
//  8 V00, 9 V10, 10 V01, 11 V11, 12 mux, 13 muy, 14 pad, 15 pad

// ---------------------------------------------------------------- K1: per-Gaussian params
__global__ void k_setup(const float* __restrict__ mu, const float* __restrict__ sigma,
                        float* __restrict__ par, unsigned* __restrict__ gm,
                        int* __restrict__ cnt) {
    int j = threadIdx.x;
    if (j >= NJ) return;
    float a = sigma[j * 4 + 0];
    float b = sigma[j * 4 + 1];
    float c = sigma[j * 4 + 3];
    // 2x2 symmetric eigendecomposition, ascending order (matches jnp.linalg.eigh)
    float mean = 0.5f * (a + c);
    float diff = 0.5f * (a - c);
    float disc = sqrtf(diff * diff + b * b);
    float l0 = mean - disc;   // smaller
    float l1 = mean + disc;   // larger
    // eigenvector for l1; sign irrelevant (only sign-invariant uses)
    float ux, uy;
    if (diff >= 0.f) { ux = diff + disc; uy = b; }
    else             { ux = b;           uy = disc - diff; }
    float nn = sqrtf(ux * ux + uy * uy);
    if (nn > 0.f) { ux /= nn; uy /= nn; } else { ux = 1.f; uy = 0.f; }
    float V00 = -uy, V10 = ux;   // column 0 (l0)
    float V01 =  ux, V11 = uy;   // column 1 (l1)
    float gmean = sqrtf(l0 * l1);
    float lsc0 = l0 / gmean * 4096.f;
    float lsc1 = l1 / gmean * 4096.f;
    float s00 = (V00 * V00 * lsc0 + V01 * V01 * lsc1) * 0.25f;
    float s01 = (V00 * V10 * lsc0 + V01 * V11 * lsc1) * 0.25f;
    float s11 = (V10 * V10 * lsc0 + V11 * V11 * lsc1) * 0.25f;
    float det = s00 * s11 - s01 * s01;
    float* pj = par + (j << 4);
    pj[0]  = rintf(mu[j * 2 + 0] * 0.5f);
    pj[1]  = rintf(mu[j * 2 + 1] * 0.5f);
    pj[2]  =  s11 / det;
    pj[3]  = -2.f * s01 / det;
    pj[4]  =  s00 / det;
    pj[5]  = 0.f;
    pj[6]  = l0;  pj[7]  = l1;
    pj[8]  = V00; pj[9]  = V10; pj[10] = V01; pj[11] = V11;
    pj[12] = mu[j * 2 + 0]; pj[13] = mu[j * 2 + 1];
    pj[14] = 0.f; pj[15] = 0.f;
    gm[j] = 0u; gm[NJ + j] = 0u;   // |rot| >= 0, so uint-bit max with init 0 is exact
    cnt[j] = 0;
}

// ---------------------------------------------------------------- K2: half-res argmin maha
// 2 pixels/thread (rows r, r+256 share the column -> shared dx). Params are
// wave-uniform: readfirstlane-hinted AoS reads -> scalar loads (s_load), off
// the LDS/VMEM pipes.
__global__ __launch_bounds__(256) void k_vor(const float* __restrict__ par,
                                             float* __restrict__ val,
                                             int* __restrict__ vor) {
    int t = blockIdx.x * 256 + threadIdx.x;   // 0..131071
    int c = t & 511;
    int r = t >> 9;                           // 0..255
    const float SCALE = 512.0f / 511.0f;      // linspace(0, 512, 512) step
    float xc = (float)c * SCALE;
    float ya = (float)r * SCALE;
    float yb = (float)(r + 256) * SCALE;
    float bestA = 3.4e38f, bestB = 3.4e38f;
    int bjA = 0, bjB = 0;
    #pragma unroll 4
    for (int j = 0; j < NJ; ++j) {
        int off = __builtin_amdgcn_readfirstlane(j << 4);  // uniform -> SGPR addr
        const float* pj = par + off;
        float mmx = pj[0], mmy = pj[1], ia = pj[2], ib2 = pj[3], ic = pj[4];
        float dx  = xc - mmx;
        float dyA = ya - mmy;
        float dyB = yb - mmy;
        // keep round-2 expression shape exactly (FP-contraction / tie stability)
        float qA = ia * dx * dx + ib2 * dx * dyA + ic * dyA * dyA;
        float qB = ia * dx * dx + ib2 * dx * dyB + ic * dyB * dyB;
        if (qA < bestA) { bestA = qA; bjA = j; }
        if (qB < bestB) { bestB = qB; bjB = j; }
    }
    int pA = r * WW + c, pB = (r + 256) * WW + c;
    val[pA] = expf(-0.5f * bestA); vor[pA] = bjA;
    val[pB] = expf(-0.5f * bestB); vor[pB] = bjB;
}

// ---------------------------------------------------------------- K3: markers + segment max
// One thread per 2x2 full-res quad. The quad shares hv, the 9 half-res vor
// neighbors (OOB-as-0 loads make the Laplacian a constant-coefficient sum),
// label/thresholds/V/mu. Segment-max via wave segmented prefix-max; only
// run-leader lanes issue global atomics.
__global__ __launch_bounds__(256) void k_markers(
        const float* __restrict__ par, const float* __restrict__ val,
        const int* __restrict__ vor, const int* __restrict__ label,
        const float* __restrict__ pos_thres, const float* __restrict__ neg_thres,
        unsigned* __restrict__ gm, int* __restrict__ cnt) {
    int q = blockIdx.x * 256 + threadIdx.x;   // 0..262143 (half-res cells)
    int a = q >> 9, b = q & 511;
    int base = a * WW + b;
    bool aM = a > 0, aP = a < 511, bM = b > 0, bP = b < 511;
    // 9 half-res vor cells, OOB -> 0 (mask == load-validity for every use)
    int hmm_ = (aM && bM) ? vor[base - 513] : 0;
    int hm0_ =  aM        ? vor[base - 512] : 0;
    int hm1_ = (aM && bP) ? vor[base - 511] : 0;
    int h0m_ =  bM        ? vor[base - 1]   : 0;
    int h00_ =              vor[base];
    int h0p_ =  bP        ? vor[base + 1]   : 0;
    int hpm_ = (aP && bM) ? vor[base + 511] : 0;
    int hp0_ =  aP        ? vor[base + 512] : 0;
    int hpp_ = (aP && bP) ? vor[base + 513] : 0;
    // exact-int Laplacian (3x3 ones, center -8, zero-padded) per full-res pixel
    int lap00 = -5 * h00_ + hmm_ + 2 * hm0_ + 2 * h0m_;
    int lap01 = -5 * h00_ + 2 * hm0_ + hm1_ + 2 * h0p_;
    int lap10 = -5 * h00_ + 2 * h0m_ + hpm_ + 2 * hp0_;
    int lap11 = -5 * h00_ + 2 * h0p_ + 2 * hp0_ + hpp_;
    int hv = h00_;
    int cls = label[hv];
    float pt = pos_thres[cls], nt = neg_thres[cls];
    const float* pj = par + (hv << 4);
    float V00 = pj[8], V10 = pj[9], V01 = pj[10], V11 = pj[11];
    float mux = pj[12], muy = pj[13];
    float m0 = -1.f, m1 = -1.f;   // r0,r1 >= 0, so -1 == "no valid pixel yet"

#define DO_PIXEL(U, V, LAP) {                                                  \
    int i = 2 * a + (U), jx = 2 * b + (V);                                     \
    float ry = ((float)i  * 511.0f) / 1023.0f;                                 \
    float rx = ((float)jx * 511.0f) / 1023.0f;                                 \
    int y0 = (int)ry; int y1 = min(y0 + 1, 511); float wy = ry - (float)y0;    \
    int x0 = (int)rx; int x1 = min(x0 + 1, 511); float wx = rx - (float)x0;    \
    float top = val[y0 * WW + x0] * (1.f - wx) + val[y0 * WW + x1] * wx;       \
    float bot = val[y1 * WW + x0] * (1.f - wx) + val[y1 * WW + x1] * wx;       \
    float vf  = top * (1.f - wy) + bot * wy;                                   \
    int mk = hv + 1;                                                           \
    if (vf < pt)     mk = 0;                                                   \
    if (vf < nt)     mk = NJ + 1;                                              \
    if ((LAP) != 0)  mk = NJ + 1;                                              \
    if (mk >= 1 && mk <= NJ) {                                                 \
        float dx = (float)jx - mux, dy = (float)i - muy;                       \
        float r0 = fabsf(V00 * dx + V10 * dy);                                 \
        float r1 = fabsf(V01 * dx + V11 * dy);                                 \
        m0 = fmaxf(m0, r0); m1 = fmaxf(m1, r1);                                \
    } }

    DO_PIXEL(0, 0, lap00)
    DO_PIXEL(0, 1, lap01)
    DO_PIXEL(1, 0, lap10)
    DO_PIXEL(1, 1, lap11)
#undef DO_PIXEL

    // wave segmented prefix-max over contiguous equal-inst runs
    int lane = threadIdx.x & 63;
    int inst = (m0 >= 0.f) ? hv : -1;
    #pragma unroll
    for (int d = 1; d < 64; d <<= 1) {
        int   oi = __shfl_up(inst, d);
        float o0 = __shfl_up(m0, d);
        float o1 = __shfl_up(m1, d);
        if (lane >= d && oi == inst) { m0 = fmaxf(m0, o0); m1 = fmaxf(m1, o1); }
    }
    int ni = __shfl_down(inst, 1);
    bool leader = (inst >= 0) && (lane == 63 || ni != inst);
    if (leader) {
        atomicMax(&gm[inst],      __float_as_uint(m0));
        atomicMax(&gm[NJ + inst], __float_as_uint(m1));
        cnt[inst] = 1;   // only >0 matters; all writers store 1
    }
}

// ---------------------------------------------------------------- K4: loss + bottom-122 mean
__global__ __launch_bounds__(128) void k_loss(
        const float* __restrict__ par, const unsigned* __restrict__ gm,
        const int* __restrict__ cnt, float* __restrict__ out) {
    __shared__ float lb[NJ];
    __shared__ float sv[NJ];
    __shared__ int   si[NJ];
    int j = threadIdx.x;

    float ls0 = par[(j << 4) + 6], ls1 = par[(j << 4) + 7];
    float m0 = __uint_as_float(gm[j]);
    float m1 = __uint_as_float(gm[NJ + j]);
    bool has = cnt[j] > 0;
    float lt0 = has ? m0 * m0 : ls0;
    float lt1 = has ? m1 * m1 : ls1;
    float whr = (ls0 + ls1) + (lt0 + lt1);
    float tr  = ls0 * lt0 + ls1 * lt1;
    float det_sqrt = sqrtf(fmaxf((ls0 * ls1) * (lt0 * lt1), FEPS));
    whr = whr - 2.f * sqrtf(fmaxf(tr + 2.f * det_sqrt, FEPS));
    float dist = sqrtf(fmaxf(whr, FEPS));
    float scale = 2.f * fmaxf(sqrtf(fmaxf(sqrtf(fmaxf(det_sqrt, FEPS)), FEPS)), FEPS);
    dist = dist / scale;
    float li = 1.f - 1.f / (1.f + log1pf(dist));
    lb[j] = li;
    sv[j] = li;
    __syncthreads();

    // total sum (tree over LDS)
    #pragma unroll
    for (int s = 64; s > 0; s >>= 1) {
        if (j < s) sv[j] += sv[j + s];
        __syncthreads();
    }
    float total = sv[0];
    __syncthreads();

    // 6 largest (keep 122 smallest = ceil(128*0.95))
    float topsum = 0.f;
    #pragma unroll
    for (int it = 0; it < 6; ++it) {
        sv[j] = lb[j]; si[j] = j;
        __syncthreads();
        #pragma unroll
        for (int s = 64; s > 0; s >>= 1) {
            if (j < s) {
                if (sv[j + s] > sv[j]) { sv[j] = sv[j + s]; si[j] = si[j + s]; }
            }
            __syncthreads();
        }
        topsum += sv[0];
        if (j == 0) lb[si[0]] = -3.4e38f;
        __syncthreads();
    }

    if (j == 0) out[0] = 1.0f * (total - topsum) / 122.f;   // LOSS_WEIGHT = 1
}

// ---------------------------------------------------------------- launch
extern "C" void kernel_launch(void* const* d_in, const int* in_sizes, int n_in,
                              void* d_out, int out_size, void* d_ws, size_t ws_size,
                              hipStream_t stream) {
    const float* mu        = (const float*)d_in[0];
    const float* sigma     = (const float*)d_in[1];
    const int*   label     = (const int*)d_in[2];
    // d_in[3] = image: unused by the reference's forward pass
    const float* pos_thres = (const float*)d_in[4];
    const float* neg_thres = (const float*)d_in[5];
    float* out = (float*)d_out;

    // workspace layout
    float*    val = (float*)d_ws;                                   // 512*512 f32 (1 MiB)
    int*      vor = (int*)((char*)d_ws + (size_t)HH * WW * 4);      // 512*512 i32 (1 MiB)
    float*    par = (float*)((char*)d_ws + 2ull * HH * WW * 4);     // 128*16 f32 (8 KiB)
    unsigned* gm  = (unsigned*)(par + NJ * 16);                     // 2*NJ u32
    int*      cnt = (int*)(gm + 2 * NJ);                            // NJ i32

    k_setup  <<<1, 128, 0, stream>>>(mu, sigma, par, gm, cnt);
    k_vor    <<<(HH * WW / 2) / 256, 256, 0, stream>>>(par, val, vor);
    k_markers<<<(HH * WW) / 256, 256, 0, stream>>>(par, val, vor, label,
                                                   pos_thres, neg_thres, gm, cnt);
    k_loss   <<<1, 128, 0, stream>>>(par, gm, cnt, out);
}

// Round 5
// 51.295 us; speedup vs baseline: 1.4908x; 1.4908x over previous
//
#include <hip/hip_runtime.h>
#include <math.h>

#define NJ 128
#define HH 512
#define WW 512
#define FEPS 1e-7f

// ---------------------------------------------------------------- shared eig helper
// 2x2 symmetric eigendecomposition, ascending order (matches jnp.linalg.eigh).
// Bit-identical to the validated k_setup of rounds 2-4.
__device__ __forceinline__ void eig2x2(float a, float b, float c,
                                       float& l0, float& l1,
                                       float& V00, float& V10, float& V01, float& V11) {
    float mean = 0.5f * (a + c);
    float diff = 0.5f * (a - c);
    float disc = sqrtf(diff * diff + b * b);
    l0 = mean - disc;   // smaller
    l1 = mean + disc;   // larger
    float ux, uy;
    if (diff >= 0.f) { ux = diff + disc; uy = b; }
    else             { ux = b;           uy = disc - diff; }
    float nn = sqrtf(ux * ux + uy * uy);
    if (nn > 0.f) { ux /= nn; uy /= nn; } else { ux = 1.f; uy = 0.f; }
    V00 = -uy; V10 = ux;   // column 0 (l0)
    V01 =  ux; V11 = uy;   // column 1 (l1)
}

// ---------------------------------------------------------------- K1: setup-in-LDS + vor
// Each block recomputes all 128 Gaussian params into its own LDS (no global par).
// 2 pixels/thread (rows r, r+256 share dx). Params read as LDS float4 broadcast
// (same-address across the wave -> conflict-free, 2 ds_reads per j instead of 5).
__global__ __launch_bounds__(256, 2) void k_vorf(
        const float* __restrict__ mu, const float* __restrict__ sigma,
        float* __restrict__ val, int* __restrict__ vor,
        unsigned* __restrict__ gm, unsigned* __restrict__ cnt,
        unsigned* __restrict__ bar) {
    __shared__ float4 lp[NJ];   // mmx, mmy, ia, ib2
    __shared__ float  lic[NJ];  // ic
    int tid = threadIdx.x;
    if (tid < NJ) {
        int j = tid;
        float a = sigma[j * 4 + 0];
        float b = sigma[j * 4 + 1];
        float c = sigma[j * 4 + 3];
        float l0, l1, V00, V10, V01, V11;
        eig2x2(a, b, c, l0, l1, V00, V10, V01, V11);
        float gmean = sqrtf(l0 * l1);
        float lsc0 = l0 / gmean * 4096.f;
        float lsc1 = l1 / gmean * 4096.f;
        float s00 = (V00 * V00 * lsc0 + V01 * V01 * lsc1) * 0.25f;
        float s01 = (V00 * V10 * lsc0 + V01 * V11 * lsc1) * 0.25f;
        float s11 = (V10 * V10 * lsc0 + V11 * V11 * lsc1) * 0.25f;
        float det = s00 * s11 - s01 * s01;
        float4 q;
        q.x = rintf(mu[j * 2 + 0] * 0.5f);   // jnp.round = ties-to-even = rintf
        q.y = rintf(mu[j * 2 + 1] * 0.5f);
        q.z =  s11 / det;                    // ia
        q.w = -2.f * s01 / det;              // ib2
        lp[j]  = q;
        lic[j] = s00 / det;                  // ic
    }
    if (blockIdx.x == 0) {                   // init cross-kernel state (stream-ordered)
        if (tid < NJ) { gm[tid] = 0u; gm[NJ + tid] = 0u; cnt[tid] = 0u; }
        if (tid == 0) *bar = 0u;
    }
    __syncthreads();

    int t = blockIdx.x * 256 + tid;          // 0..131071
    int c = t & 511;
    int r = t >> 9;                          // 0..255
    const float SCALE = 512.0f / 511.0f;     // linspace(0, 512, 512) step
    float xc = (float)c * SCALE;
    float ya = (float)r * SCALE;
    float yb = (float)(r + 256) * SCALE;
    float bestA = 3.4e38f, bestB = 3.4e38f;
    int bjA = 0, bjB = 0;
    #pragma unroll 4
    for (int j = 0; j < NJ; ++j) {
        float4 p = lp[j];
        float ic = lic[j];
        float dx  = xc - p.x;
        float dyA = ya - p.y;
        float dyB = yb - p.y;
        // identical expression shape to validated rounds (FP contraction / ties)
        float qA = p.z * dx * dx + p.w * dx * dyA + ic * dyA * dyA;
        float qB = p.z * dx * dx + p.w * dx * dyB + ic * dyB * dyB;
        if (qA < bestA) { bestA = qA; bjA = j; }   // first index on ties
        if (qB < bestB) { bestB = qB; bjB = j; }
    }
    int pA = r * WW + c, pB = (r + 256) * WW + c;
    val[pA] = expf(-0.5f * bestA); vor[pA] = bjA;
    val[pB] = expf(-0.5f * bestB); vor[pB] = bjB;
}

// ---------------------------------------------------------------- K2: markers + loss (last block)
// Quad-per-thread markers (validated round 4), params + pre-resolved thresholds
// in LDS. Segment-max via wave segmented prefix-max; leaders do device-scope
// atomics. The LAST block to finish (atomic counter) computes the final loss.
__global__ __launch_bounds__(256, 2) void k_markf(
        const float* __restrict__ mu, const float* __restrict__ sigma,
        const int* __restrict__ label, const float* __restrict__ pos_thres,
        const float* __restrict__ neg_thres,
        const float* __restrict__ val, const int* __restrict__ vor,
        unsigned* __restrict__ gm, unsigned* __restrict__ cnt,
        unsigned* __restrict__ bar, float* __restrict__ out) {
    __shared__ float4 lv[NJ];     // V00, V10, V01, V11
    __shared__ float2 lmu[NJ];    // mux, muy
    __shared__ float  lpt[NJ], lnt[NJ];
    __shared__ float  lls0[NJ], lls1[NJ];
    __shared__ float  lb[NJ], sv[NJ];
    __shared__ int    si[NJ];
    __shared__ int    isLast;
    int tid = threadIdx.x;
    if (tid < NJ) {
        int j = tid;
        float a = sigma[j * 4 + 0];
        float b = sigma[j * 4 + 1];
        float cc = sigma[j * 4 + 3];
        float l0, l1, V00, V10, V01, V11;
        eig2x2(a, b, cc, l0, l1, V00, V10, V01, V11);
        lv[j]  = make_float4(V00, V10, V01, V11);
        lmu[j] = make_float2(mu[j * 2 + 0], mu[j * 2 + 1]);
        int cl = label[j];
        lpt[j] = pos_thres[cl];
        lnt[j] = neg_thres[cl];
        lls0[j] = l0; lls1[j] = l1;
    }
    __syncthreads();

    int q = blockIdx.x * 256 + tid;   // 0..262143 half-res cells (2x2 quads)
    int a = q >> 9, b = q & 511;
    int base = a * WW + b;
    bool aM = a > 0, aP = a < 511, bM = b > 0, bP = b < 511;
    // 9 half-res vor cells, OOB -> 0 (mask == load-validity for every use)
    int hmm_ = (aM && bM) ? vor[base - 513] : 0;
    int hm0_ =  aM        ? vor[base - 512] : 0;
    int hm1_ = (aM && bP) ? vor[base - 511] : 0;
    int h0m_ =  bM        ? vor[base - 1]   : 0;
    int h00_ =              vor[base];
    int h0p_ =  bP        ? vor[base + 1]   : 0;
    int hpm_ = (aP && bM) ? vor[base + 511] : 0;
    int hp0_ =  aP        ? vor[base + 512] : 0;
    int hpp_ = (aP && bP) ? vor[base + 513] : 0;
    // exact-int Laplacian (3x3 ones, center -8, zero-padded) per full-res pixel
    int lap00 = -5 * h00_ + hmm_ + 2 * hm0_ + 2 * h0m_;
    int lap01 = -5 * h00_ + 2 * hm0_ + hm1_ + 2 * h0p_;
    int lap10 = -5 * h00_ + 2 * h0m_ + hpm_ + 2 * hp0_;
    int lap11 = -5 * h00_ + 2 * h0p_ + 2 * hp0_ + hpp_;
    int hv = h00_;
    float  pt = lpt[hv], nt = lnt[hv];
    float4 Vv = lv[hv];
    float2 mv = lmu[hv];
    float m0 = -1.f, m1 = -1.f;   // r0,r1 >= 0, so -1 == "no valid pixel yet"

#define DO_PIXEL(U, V, LAP) {                                                  \
    int i = 2 * a + (U), jx = 2 * b + (V);                                     \
    float ry = ((float)i  * 511.0f) / 1023.0f;                                 \
    float rx = ((float)jx * 511.0f) / 1023.0f;                                 \
    int y0 = (int)ry; int y1 = min(y0 + 1, 511); float wy = ry - (float)y0;    \
    int x0 = (int)rx; int x1 = min(x0 + 1, 511); float wx = rx - (float)x0;    \
    float top = val[y0 * WW + x0] * (1.f - wx) + val[y0 * WW + x1] * wx;       \
    float bot = val[y1 * WW + x0] * (1.f - wx) + val[y1 * WW + x1] * wx;       \
    float vf  = top * (1.f - wy) + bot * wy;                                   \
    int mk = hv + 1;                                                           \
    if (vf < pt)     mk = 0;                                                   \
    if (vf < nt)     mk = NJ + 1;                                              \
    if ((LAP) != 0)  mk = NJ + 1;                                              \
    if (mk >= 1 && mk <= NJ) {                                                 \
        float dx = (float)jx - mv.x, dy = (float)i - mv.y;                     \
        float r0 = fabsf(Vv.x * dx + Vv.y * dy);                               \
        float r1 = fabsf(Vv.z * dx + Vv.w * dy);                               \
        m0 = fmaxf(m0, r0); m1 = fmaxf(m1, r1);                                \
    } }

    DO_PIXEL(0, 0, lap00)
    DO_PIXEL(0, 1, lap01)
    DO_PIXEL(1, 0, lap10)
    DO_PIXEL(1, 1, lap11)
#undef DO_PIXEL

    // wave segmented prefix-max over contiguous equal-inst runs
    int lane = tid & 63;
    int inst = (m0 >= 0.f) ? hv : -1;
    #pragma unroll
    for (int d = 1; d < 64; d <<= 1) {
        int   oi = __shfl_up(inst, d);
        float o0 = __shfl_up(m0, d);
        float o1 = __shfl_up(m1, d);
        if (lane >= d && oi == inst) { m0 = fmaxf(m0, o0); m1 = fmaxf(m1, o1); }
    }
    int ni = __shfl_down(inst, 1);
    bool leader = (inst >= 0) && (lane == 63 || ni != inst);
    if (leader) {   // device-scope atomics: coherent across XCDs
        atomicMax(&gm[inst],      __float_as_uint(m0));
        atomicMax(&gm[NJ + inst], __float_as_uint(m1));
        atomicOr (&cnt[inst], 1u);
    }

    // last-block-done: __syncthreads drains vmcnt, so all this block's atomics
    // reached the coherence point before tid0 increments the counter.
    __syncthreads();
    if (tid == 0) {
        unsigned done = atomicAdd(bar, 1u);
        isLast = (done == gridDim.x - 1) ? 1 : 0;
    }
    __syncthreads();
    if (!isLast) return;

    // ---------------- loss phase (entire last block participates in barriers)
    if (tid < NJ) {
        float ls0 = lls0[tid], ls1 = lls1[tid];
        float g0 = __uint_as_float(atomicMax(&gm[tid], 0u));        // coherent read
        float g1 = __uint_as_float(atomicMax(&gm[NJ + tid], 0u));
        unsigned has = atomicAdd(&cnt[tid], 0u);
        float lt0 = has ? g0 * g0 : ls0;
        float lt1 = has ? g1 * g1 : ls1;
        float whr = (ls0 + ls1) + (lt0 + lt1);
        float tr  = ls0 * lt0 + ls1 * lt1;
        float det_sqrt = sqrtf(fmaxf((ls0 * ls1) * (lt0 * lt1), FEPS));
        whr = whr - 2.f * sqrtf(fmaxf(tr + 2.f * det_sqrt, FEPS));
        float dist = sqrtf(fmaxf(whr, FEPS));
        float scale = 2.f * fmaxf(sqrtf(fmaxf(sqrtf(fmaxf(det_sqrt, FEPS)), FEPS)), FEPS);
        dist = dist / scale;
        float li = 1.f - 1.f / (1.f + log1pf(dist));
        lb[tid] = li;
        sv[tid] = li;
    }
    __syncthreads();

    // total sum (tree over LDS)
    #pragma unroll
    for (int s = 64; s > 0; s >>= 1) {
        if (tid < s) sv[tid] += sv[tid + s];
        __syncthreads();
    }
    float total = sv[0];
    __syncthreads();

    // 6 largest (keep 122 smallest = ceil(128*0.95))
    float topsum = 0.f;
    #pragma unroll
    for (int it = 0; it < 6; ++it) {
        if (tid < NJ) { sv[tid] = lb[tid]; si[tid] = tid; }
        __syncthreads();
        #pragma unroll
        for (int s = 64; s > 0; s >>= 1) {
            if (tid < s) {
                if (sv[tid + s] > sv[tid]) { sv[tid] = sv[tid + s]; si[tid] = si[tid + s]; }
            }
            __syncthreads();
        }
        topsum += sv[0];
        if (tid == 0) lb[si[0]] = -3.4e38f;
        __syncthreads();
    }

    if (tid == 0) out[0] = 1.0f * (total - topsum) / 122.f;   // LOSS_WEIGHT = 1
}

// ---------------------------------------------------------------- launch
extern "C" void kernel_launch(void* const* d_in, const int* in_sizes, int n_in,
                              void* d_out, int out_size, void* d_ws, size_t ws_size,
                              hipStream_t stream) {
    const float* mu        = (const float*)d_in[0];
    const float* sigma     = (const float*)d_in[1];
    const int*   label     = (const int*)d_in[2];
    // d_in[3] = image: unused by the reference's forward pass
    const float* pos_thres = (const float*)d_in[4];
    const float* neg_thres = (const float*)d_in[5];
    float* out = (float*)d_out;

    // workspace layout
    float*    val = (float*)d_ws;                                   // 512*512 f32 (1 MiB)
    int*      vor = (int*)((char*)d_ws + (size_t)HH * WW * 4);      // 512*512 i32 (1 MiB)
    unsigned* gm  = (unsigned*)((char*)d_ws + 2ull * HH * WW * 4);  // 2*NJ u32
    unsigned* cnt = gm + 2 * NJ;                                    // NJ u32
    unsigned* bar = cnt + NJ;                                       // 1 u32

    k_vorf <<<(HH * WW / 2) / 256, 256, 0, stream>>>(mu, sigma, val, vor, gm, cnt, bar);
    k_markf<<<(HH * WW) / 256, 256, 0, stream>>>(mu, sigma, label, pos_thres, neg_thres,
                                                 val, vor, gm, cnt, bar, out);
}